// Round 1
// baseline (1677.533 us; speedup 1.0000x reference)
//
#include <hip/hip_runtime.h>
#include <hip/hip_bf16.h>
#include <math.h>

#define BB 2
#define NN 4096
#define DD 512
#define FF 257
#define FP 288            // padded freq bins (9 chunks of 32)
#define PI_F 3.14159265358979323846f

// ---- workspace layout (bytes) ----
#define M_OFF   0
#define M_BYTES ((size_t)DD * FF * 2 * 4)                 // float2 M[512][257]
#define XN_OFF  1052672                                    // == M_BYTES (aligned)
#define XN_BYTES ((size_t)BB * NN * FP * 2 * 4)            // float2 xn[B][N][288]
#define SS_OFF  (XN_OFF + 18874368)                        // 19927040
#define SS_BYTES ((size_t)BB * NN * NN * 2)                // bf16 softmax weights
#define MX_OFF  (SS_OFF + 67108864)                        // 87035904
#define MX_BYTES ((size_t)BB * NN * DD * 4)

static __device__ __forceinline__ unsigned short f2bf(float f) {
    unsigned int u = __float_as_uint(f);
    unsigned int r = (u + 0x7fffu + ((u >> 16) & 1u)) >> 16;   // RNE
    return (unsigned short)r;
}
static __device__ __forceinline__ float bf2f(unsigned short s) {
    return __uint_as_float(((unsigned int)s) << 16);
}

// ---------------------------------------------------------------------------
// M[d][g] = sum_f W[g,f] * exp(-2*pi*i*f*d/512)   (store as float2, [512][257])
__global__ __launch_bounds__(320) void k_build_M(const float* __restrict__ W,
                                                 float* __restrict__ M) {
    __shared__ float twr[512], twi[512];
    const int d = blockIdx.x;
    const int tid = threadIdx.x;
    for (int k = tid; k < 512; k += 320) {
        float ang = -(2.0f * PI_F / 512.0f) * (float)k;
        float s, c;
        sincosf(ang, &s, &c);
        twr[k] = c; twi[k] = s;
    }
    __syncthreads();
    const int g = tid;
    if (g < FF) {
        float re = 0.f, im = 0.f;
        const float* __restrict__ wrow = W + g * FF;
        for (int f = 0; f < FF; ++f) {
            float w = wrow[f];
            int k = (f * d) & 511;
            re = fmaf(w, twr[k], re);
            im = fmaf(w, twi[k], im);
        }
        ((float2*)M)[d * FF + g] = make_float2(re, im);
    }
}

// ---------------------------------------------------------------------------
// Per token t: xp[g] = sum_d x[t,d] * M[d][g]; norm; write xn[b][t][g] float2,
// zero-pad g in [257,288). 16 tokens per block, thread = g.
__global__ __launch_bounds__(320) void k_proj_norm(const float* __restrict__ x,
                                                   const float* __restrict__ M,
                                                   float* __restrict__ xn) {
    __shared__ float xs[16][512];
    __shared__ float ssq[16];
    const int b = blockIdx.y;
    const int t0 = blockIdx.x * 16;
    const int tid = threadIdx.x;
    const float* __restrict__ xp = x + ((size_t)(b * NN + t0)) * DD;
    for (int i4 = tid; i4 < 16 * 512 / 4; i4 += 320) {
        float4 v = ((const float4*)xp)[i4];
        *(float4*)&xs[0][i4 * 4] = v;
    }
    if (tid < 16) ssq[tid] = 0.f;
    __syncthreads();

    const int g = tid;
    float accr[16], acci[16];
#pragma unroll
    for (int t = 0; t < 16; ++t) { accr[t] = 0.f; acci[t] = 0.f; }

    if (g < FF) {
        const float2* __restrict__ M2 = (const float2*)M;
        for (int d = 0; d < DD; d += 4) {
            float2 m0 = M2[(d + 0) * FF + g];
            float2 m1 = M2[(d + 1) * FF + g];
            float2 m2 = M2[(d + 2) * FF + g];
            float2 m3 = M2[(d + 3) * FF + g];
#pragma unroll
            for (int t = 0; t < 16; ++t) {
                float4 xv = *(const float4*)&xs[t][d];
                float r = accr[t], i = acci[t];
                r = fmaf(xv.x, m0.x, r); i = fmaf(xv.x, m0.y, i);
                r = fmaf(xv.y, m1.x, r); i = fmaf(xv.y, m1.y, i);
                r = fmaf(xv.z, m2.x, r); i = fmaf(xv.z, m2.y, i);
                r = fmaf(xv.w, m3.x, r); i = fmaf(xv.w, m3.y, i);
                accr[t] = r; acci[t] = i;
            }
        }
    }
#pragma unroll
    for (int t = 0; t < 16; ++t) {
        float v = (g < FF) ? fmaf(accr[t], accr[t], acci[t] * acci[t]) : 0.f;
        for (int off = 32; off > 0; off >>= 1) v += __shfl_down(v, off, 64);
        if ((tid & 63) == 0) atomicAdd(&ssq[t], v);
    }
    __syncthreads();
    if (g < FP) {
        float2* __restrict__ xrow = (float2*)xn;
#pragma unroll
        for (int t = 0; t < 16; ++t) {
            float rn = (g < FF) ? rsqrtf(ssq[t] + 1e-8f) : 0.f;
            float2 v;
            v.x = (g < FF) ? accr[t] * rn : 0.f;
            v.y = (g < FF) ? acci[t] * rn : 0.f;
            xrow[((size_t)(b * NN + t0 + t)) * FP + g] = v;
        }
    }
}

// ---------------------------------------------------------------------------
// S[b][r][c] = | sum_g xn[r,g] * conj(xn[c,g]) |   64x64 tile / block, 4x4/thread
__global__ __launch_bounds__(256) void k_gram(const float* __restrict__ xn,
                                              float* __restrict__ Sout) {
    __shared__ float As[64][68];
    __shared__ float Bs[64][68];
    const int b = blockIdx.z;
    const int brow = blockIdx.y * 64;
    const int bcol = blockIdx.x * 64;
    const int tid = threadIdx.x;
    const int tx = tid & 15, ty = tid >> 4;
    float r_re[4][4] = {{0.f}}, r_im[4][4] = {{0.f}};
    const float* __restrict__ Abase = xn + (size_t)(b * NN + brow) * (FP * 2);
    const float* __restrict__ Bbase = xn + (size_t)(b * NN + bcol) * (FP * 2);
    for (int kc = 0; kc < FP / 32; ++kc) {    // 9 chunks of 32 complex (64 floats)
        __syncthreads();
#pragma unroll
        for (int u = 0; u < 4; ++u) {
            int idx = tid + u * 256;          // 0..1023
            int row = idx >> 4, c4 = idx & 15;
            float4 va = *(const float4*)(Abase + (size_t)row * (FP * 2) + kc * 64 + c4 * 4);
            *(float4*)&As[row][c4 * 4] = va;
            float4 vb = *(const float4*)(Bbase + (size_t)row * (FP * 2) + kc * 64 + c4 * 4);
            *(float4*)&Bs[row][c4 * 4] = vb;
        }
        __syncthreads();
#pragma unroll 8
        for (int k = 0; k < 32; ++k) {
            float2 a[4], bb[4];
#pragma unroll
            for (int i = 0; i < 4; ++i) a[i] = *(const float2*)&As[ty + 16 * i][2 * k];
#pragma unroll
            for (int j = 0; j < 4; ++j) bb[j] = *(const float2*)&Bs[tx + 16 * j][2 * k];
#pragma unroll
            for (int i = 0; i < 4; ++i)
#pragma unroll
                for (int j = 0; j < 4; ++j) {
                    r_re[i][j] = fmaf(a[i].x, bb[j].x, r_re[i][j]);
                    r_re[i][j] = fmaf(a[i].y, bb[j].y, r_re[i][j]);
                    r_im[i][j] = fmaf(a[i].y, bb[j].x, r_im[i][j]);
                    r_im[i][j] = fmaf(-a[i].x, bb[j].y, r_im[i][j]);
                }
        }
    }
    float* __restrict__ Srow = Sout + (size_t)b * NN * NN;
#pragma unroll
    for (int i = 0; i < 4; ++i) {
        int r = brow + ty + 16 * i;
#pragma unroll
        for (int j = 0; j < 4; ++j) {
            int c = bcol + tx + 16 * j;
            float re = r_re[i][j], im = r_im[i][j];
            Srow[(size_t)r * NN + c] = sqrtf(fmaf(re, re, im * im));
        }
    }
}

// ---------------------------------------------------------------------------
// row softmax of S/2 -> bf16 weights
__global__ __launch_bounds__(256) void k_softmax(const float* __restrict__ S,
                                                 unsigned short* __restrict__ Wout) {
    __shared__ float red[8];
    const size_t row = blockIdx.x;            // 0..B*N-1
    const int tid = threadIdx.x;
    const float4* __restrict__ p4 = (const float4*)(S + row * NN);
    float4 v[4];
    float vmax = -1e30f;
#pragma unroll
    for (int u = 0; u < 4; ++u) {
        v[u] = p4[u * 256 + tid];
        vmax = fmaxf(vmax, fmaxf(fmaxf(v[u].x, v[u].y), fmaxf(v[u].z, v[u].w)));
    }
    for (int off = 32; off > 0; off >>= 1) vmax = fmaxf(vmax, __shfl_down(vmax, off, 64));
    if ((tid & 63) == 0) red[tid >> 6] = vmax;
    __syncthreads();
    const float bmax = fmaxf(fmaxf(red[0], red[1]), fmaxf(red[2], red[3]));
    float s = 0.f;
#pragma unroll
    for (int u = 0; u < 4; ++u) {
        v[u].x = __expf((v[u].x - bmax) * 0.5f);
        v[u].y = __expf((v[u].y - bmax) * 0.5f);
        v[u].z = __expf((v[u].z - bmax) * 0.5f);
        v[u].w = __expf((v[u].w - bmax) * 0.5f);
        s += (v[u].x + v[u].y) + (v[u].z + v[u].w);
    }
    for (int off = 32; off > 0; off >>= 1) s += __shfl_down(s, off, 64);
    if ((tid & 63) == 0) red[4 + (tid >> 6)] = s;
    __syncthreads();
    const float rinv = 1.0f / ((red[4] + red[5]) + (red[6] + red[7]));
    ushort4* __restrict__ o4 = (ushort4*)(Wout + row * NN);
#pragma unroll
    for (int u = 0; u < 4; ++u) {
        ushort4 w;
        w.x = f2bf(v[u].x * rinv);
        w.y = f2bf(v[u].y * rinv);
        w.z = f2bf(v[u].z * rinv);
        w.w = f2bf(v[u].w * rinv);
        o4[u * 256 + tid] = w;
    }
}

// ---------------------------------------------------------------------------
// mixed = Ssoft @ x : (N x N bf16) @ (N x D f32), 64x64 tiles, 4x4/thread
__global__ __launch_bounds__(256) void k_mixed(const unsigned short* __restrict__ Ws,
                                               const float* __restrict__ x,
                                               float* __restrict__ mixed) {
    __shared__ unsigned short As[64][40];   // 64 rows x 32 k (pad->40)
    __shared__ float Bs[32][68];            // 32 k x 64 cols (pad->68)
    const int b = blockIdx.z;
    const int brow = blockIdx.y * 64;
    const int bcol = blockIdx.x * 64;
    const int tid = threadIdx.x;
    const int tx = tid & 15, ty = tid >> 4;
    float acc[4][4] = {{0.f}};
    const unsigned short* __restrict__ Abase = Ws + (size_t)(b * NN + brow) * NN;
    const float* __restrict__ Bbase = x + (size_t)b * NN * DD + bcol;
    for (int kc = 0; kc < NN / 32; ++kc) {
        __syncthreads();
        {
            int row = tid >> 2, c = tid & 3;     // 8 ushorts (16B) per thread
            uint4 av = *(const uint4*)(Abase + (size_t)row * NN + kc * 32 + c * 8);
            *(uint4*)&As[row][c * 8] = av;
        }
#pragma unroll
        for (int u = 0; u < 2; ++u) {
            int idx = tid + u * 256;             // 0..511
            int k = idx >> 4, c4 = idx & 15;
            float4 bv = *(const float4*)(Bbase + (size_t)(kc * 32 + k) * DD + c4 * 4);
            *(float4*)&Bs[k][c4 * 4] = bv;
        }
        __syncthreads();
#pragma unroll 8
        for (int k = 0; k < 32; ++k) {
            float a[4], bb[4];
#pragma unroll
            for (int i = 0; i < 4; ++i) a[i] = bf2f(As[ty + 16 * i][k]);
#pragma unroll
            for (int j = 0; j < 4; ++j) bb[j] = Bs[k][tx + 16 * j];
#pragma unroll
            for (int i = 0; i < 4; ++i)
#pragma unroll
                for (int j = 0; j < 4; ++j) acc[i][j] = fmaf(a[i], bb[j], acc[i][j]);
        }
    }
    float* __restrict__ outb = mixed + (size_t)b * NN * DD;
#pragma unroll
    for (int i = 0; i < 4; ++i)
#pragma unroll
        for (int j = 0; j < 4; ++j)
            outb[(size_t)(brow + ty + 16 * i) * DD + (bcol + tx + 16 * j)] = acc[i][j];
}

// ---------------------------------------------------------------------------
// h = x + 0.3*(mixed - x); LayerNorm(D) * gamma + beta
__global__ __launch_bounds__(256) void k_ln(const float* __restrict__ x,
                                            const float* __restrict__ mixed,
                                            const float* __restrict__ gamma,
                                            const float* __restrict__ beta,
                                            float* __restrict__ out) {
    __shared__ float red[8];
    const size_t row = blockIdx.x;
    const int tid = threadIdx.x;
    const float* __restrict__ xr = x + row * DD;
    const float* __restrict__ mr = mixed + row * DD;
    float x0 = xr[tid], x1 = xr[tid + 256];
    float h0 = fmaf(0.3f, mr[tid] - x0, x0);
    float h1 = fmaf(0.3f, mr[tid + 256] - x1, x1);
    float s = h0 + h1;
    float sq = fmaf(h0, h0, h1 * h1);
    for (int off = 32; off > 0; off >>= 1) {
        s += __shfl_down(s, off, 64);
        sq += __shfl_down(sq, off, 64);
    }
    if ((tid & 63) == 0) { red[tid >> 6] = s; red[4 + (tid >> 6)] = sq; }
    __syncthreads();
    const float mu = ((red[0] + red[1]) + (red[2] + red[3])) * (1.0f / DD);
    const float var = ((red[4] + red[5]) + (red[6] + red[7])) * (1.0f / DD) - mu * mu;
    const float rstd = rsqrtf(var + 1e-5f);
    out[row * DD + tid] = fmaf((h0 - mu) * rstd, gamma[tid], beta[tid]);
    out[row * DD + tid + 256] = fmaf((h1 - mu) * rstd, gamma[tid + 256], beta[tid + 256]);
}

// ---------------------------------------------------------------------------
extern "C" void kernel_launch(void* const* d_in, const int* in_sizes, int n_in,
                              void* d_out, int out_size, void* d_ws, size_t ws_size,
                              hipStream_t stream) {
    const float* x     = (const float*)d_in[0];
    const float* Wspec = (const float*)d_in[1];
    const float* gamma = (const float*)d_in[2];
    const float* beta  = (const float*)d_in[3];
    float* out  = (float*)d_out;                       // [B][N][D]
    float* Sout = out + (size_t)BB * NN * DD;          // [B][N][N]

    char* ws = (char*)d_ws;
    float* M              = (float*)(ws + M_OFF);
    float* xn             = (float*)(ws + XN_OFF);
    unsigned short* Ssoft = (unsigned short*)(ws + SS_OFF);
    float* mixed          = (float*)(ws + MX_OFF);

    hipLaunchKernelGGL(k_build_M, dim3(512), dim3(320), 0, stream, Wspec, M);
    hipLaunchKernelGGL(k_proj_norm, dim3(NN / 16, BB), dim3(320), 0, stream, x, M, xn);
    hipLaunchKernelGGL(k_gram, dim3(NN / 64, NN / 64, BB), dim3(256), 0, stream, xn, Sout);
    hipLaunchKernelGGL(k_softmax, dim3(BB * NN), dim3(256), 0, stream, Sout, Ssoft);
    hipLaunchKernelGGL(k_mixed, dim3(DD / 64, NN / 64, BB), dim3(256), 0, stream, Ssoft, x, mixed);
    hipLaunchKernelGGL(k_ln, dim3(BB * NN), dim3(256), 0, stream, x, mixed, gamma, beta, out);
}

// Round 4
// 529.143 us; speedup vs baseline: 3.1703x; 3.1703x over previous
//
#include <hip/hip_runtime.h>
#include <hip/hip_bf16.h>
#include <math.h>

#define BB 2
#define NN 4096
#define DD 512
#define FF 257
#define FP 288            // padded complex freq bins
#define KK2 (2*FP)        // 576 bf16 along K for gram
#define PI_F 3.14159265358979323846f

typedef __attribute__((ext_vector_type(4))) float f32x4;
typedef __attribute__((ext_vector_type(8))) short bf16x8;
typedef unsigned int u32;
typedef unsigned short u16;

// ---- workspace layout (bytes) ----
#define M_OFF   0u          // float2 M[512][257]           = 1,052,672
#define XF_OFF  1052672u    // bf16 Xf[2][4096][576]        = 9,437,184
#define SS_OFF  10489856u   // bf16 Ssoft[2][4096][4096]    = 67,108,864
#define XT_OFF  77598720u   // bf16 xbT[2][512][4096]       = 8,388,608
#define MX_OFF  85987328u   // f32 mixed[2][4096][512]      = 16,777,216  (end 102,764,544)

#define AS1 __attribute__((address_space(1)))
#define AS3 __attribute__((address_space(3)))

static __device__ __forceinline__ void gl2lds(const u16* g, u16* l) {
    __builtin_amdgcn_global_load_lds((const AS1 u32*)(unsigned long long)g,
                                     (AS3 u32*)(unsigned)(unsigned long long)l,
                                     16, 0, 0);
}

static __device__ __forceinline__ unsigned short f2bf(float f) {
    unsigned int u = __float_as_uint(f);
    unsigned int r = (u + 0x7fffu + ((u >> 16) & 1u)) >> 16;   // RNE
    return (unsigned short)r;
}
static __device__ __forceinline__ float bf2f(unsigned short s) {
    return __uint_as_float(((unsigned int)s) << 16);
}

// (re,im) bf16 pair per dword -> (im, -re)
static __device__ __forceinline__ bf16x8 conj_swap(bf16x8 a) {
    union { bf16x8 v; u32 u[4]; } s, d;
    s.v = a;
#pragma unroll
    for (int i = 0; i < 4; ++i) {
        u32 w = s.u[i];
        d.u[i] = ((w >> 16) | (w << 16)) ^ 0x80000000u;
    }
    return d.v;
}

// ---------------------------------------------------------------------------
// M[d][g] = sum_f W[g,f] * exp(-2*pi*i*f*d/512)   (float2, [512][257])
__global__ __launch_bounds__(320) void k_build_M(const float* __restrict__ W,
                                                 float* __restrict__ M) {
    __shared__ float twr[512], twi[512];
    const int d = blockIdx.x;
    const int tid = threadIdx.x;
    for (int k = tid; k < 512; k += 320) {
        float ang = -(2.0f * PI_F / 512.0f) * (float)k;
        float s, c;
        sincosf(ang, &s, &c);
        twr[k] = c; twi[k] = s;
    }
    __syncthreads();
    const int g = tid;
    if (g < FF) {
        float re = 0.f, im = 0.f;
        const float* __restrict__ wrow = W + g * FF;
        for (int f = 0; f < FF; ++f) {
            float w = wrow[f];
            int k = (f * d) & 511;
            re = fmaf(w, twr[k], re);
            im = fmaf(w, twi[k], im);
        }
        ((float2*)M)[d * FF + g] = make_float2(re, im);
    }
}

// ---------------------------------------------------------------------------
// Per token: x_hat[g] = sum_d x[t,d]*M[d][g]; normalize; write bf16 interleaved
// Xf[b][t][2g]=re, [2g+1]=im, zero pad g in [257,288).
__global__ __launch_bounds__(320) void k_proj_norm(const float* __restrict__ x,
                                                   const float* __restrict__ M,
                                                   u32* __restrict__ Xf) {
    __shared__ float xs[16][512];
    __shared__ float ssq[16];
    const int b = blockIdx.y;
    const int t0 = blockIdx.x * 16;
    const int tid = threadIdx.x;
    const float* __restrict__ xp = x + ((size_t)(b * NN + t0)) * DD;
    for (int i4 = tid; i4 < 16 * 512 / 4; i4 += 320) {
        float4 v = ((const float4*)xp)[i4];
        *(float4*)&xs[0][i4 * 4] = v;
    }
    if (tid < 16) ssq[tid] = 0.f;
    __syncthreads();

    const int g = tid;
    float accr[16], acci[16];
#pragma unroll
    for (int t = 0; t < 16; ++t) { accr[t] = 0.f; acci[t] = 0.f; }

    if (g < FF) {
        const float2* __restrict__ M2 = (const float2*)M;
        for (int d = 0; d < DD; d += 4) {
            float2 m0 = M2[(d + 0) * FF + g];
            float2 m1 = M2[(d + 1) * FF + g];
            float2 m2 = M2[(d + 2) * FF + g];
            float2 m3 = M2[(d + 3) * FF + g];
#pragma unroll
            for (int t = 0; t < 16; ++t) {
                float4 xv = *(const float4*)&xs[t][d];
                float r = accr[t], i = acci[t];
                r = fmaf(xv.x, m0.x, r); i = fmaf(xv.x, m0.y, i);
                r = fmaf(xv.y, m1.x, r); i = fmaf(xv.y, m1.y, i);
                r = fmaf(xv.z, m2.x, r); i = fmaf(xv.z, m2.y, i);
                r = fmaf(xv.w, m3.x, r); i = fmaf(xv.w, m3.y, i);
                accr[t] = r; acci[t] = i;
            }
        }
    }
#pragma unroll
    for (int t = 0; t < 16; ++t) {
        float v = (g < FF) ? fmaf(accr[t], accr[t], acci[t] * acci[t]) : 0.f;
        for (int off = 32; off > 0; off >>= 1) v += __shfl_down(v, off, 64);
        if ((tid & 63) == 0) atomicAdd(&ssq[t], v);
    }
    __syncthreads();
    if (g < FP) {
#pragma unroll
        for (int t = 0; t < 16; ++t) {
            u32 w = 0u;
            if (g < FF) {
                float rn = rsqrtf(ssq[t] + 1e-8f);
                w = (u32)f2bf(accr[t] * rn) | ((u32)f2bf(acci[t] * rn) << 16);
            }
            Xf[((size_t)(b * NN + t0 + t)) * FP + g] = w;
        }
    }
}

// ---------------------------------------------------------------------------
// S = |Xn Xn^H| via bf16 MFMA. 128x128 tile, BK=64, 4 waves, 2 accumulators
// (re: A=Xf, im: A=conj_swap(Xf) in-register), B tile = Xf rows of col block.
__global__ __launch_bounds__(256) void k_gram_mfma(const u16* __restrict__ Xf,
                                                   float* __restrict__ Sout) {
    __shared__ u16 Af[128 * 64];
    __shared__ u16 Bf[128 * 64];
    const int b = blockIdx.z;
    const int brow = blockIdx.y * 128;
    const int bcol = blockIdx.x * 128;
    const int tid = threadIdx.x;
    const int lane = tid & 63;
    const int wave = tid >> 6;
    const int wr = (wave >> 1) * 64;
    const int wc = (wave & 1) * 64;
    const int fr = lane & 15;
    const int fk = (lane >> 4) * 8;

    const u16* __restrict__ Arow = Xf + (size_t)(b * NN + brow) * KK2;
    const u16* __restrict__ Brow = Xf + (size_t)(b * NN + bcol) * KK2;

    f32x4 acc_re[4][4], acc_im[4][4];
#pragma unroll
    for (int m = 0; m < 4; ++m)
#pragma unroll
        for (int n = 0; n < 4; ++n) {
            acc_re[m][n] = (f32x4)0.f;
            acc_im[m][n] = (f32x4)0.f;
        }

    for (int kc = 0; kc < KK2 / 64; ++kc) {
        const int k0 = kc * 64;
        __syncthreads();
#pragma unroll
        for (int it = 0; it < 4; ++it) {
            int e = tid + it * 256;          // 0..1023
            int row = e >> 3, ch = e & 7;
            gl2lds(Arow + (size_t)row * KK2 + k0 + ch * 8, &Af[e * 8]);
            gl2lds(Brow + (size_t)row * KK2 + k0 + ch * 8, &Bf[e * 8]);
        }
        __syncthreads();
#pragma unroll
        for (int kk = 0; kk < 2; ++kk) {
            bf16x8 av[4], bv[4], gv[4];
#pragma unroll
            for (int m = 0; m < 4; ++m)
                av[m] = *(const bf16x8*)&Af[(wr + m * 16 + fr) * 64 + kk * 32 + fk];
#pragma unroll
            for (int n = 0; n < 4; ++n)
                bv[n] = *(const bf16x8*)&Bf[(wc + n * 16 + fr) * 64 + kk * 32 + fk];
#pragma unroll
            for (int m = 0; m < 4; ++m) gv[m] = conj_swap(av[m]);
#pragma unroll
            for (int m = 0; m < 4; ++m)
#pragma unroll
                for (int n = 0; n < 4; ++n) {
                    acc_re[m][n] = __builtin_amdgcn_mfma_f32_16x16x32_bf16(av[m], bv[n], acc_re[m][n], 0, 0, 0);
                    acc_im[m][n] = __builtin_amdgcn_mfma_f32_16x16x32_bf16(gv[m], bv[n], acc_im[m][n], 0, 0, 0);
                }
        }
    }

    float* __restrict__ Sb = Sout + (size_t)b * NN * NN;
#pragma unroll
    for (int m = 0; m < 4; ++m) {
#pragma unroll
        for (int reg = 0; reg < 4; ++reg) {
            int r = brow + wr + m * 16 + (lane >> 4) * 4 + reg;
            float* __restrict__ rp = Sb + (size_t)r * NN + bcol + wc + fr;
#pragma unroll
            for (int n = 0; n < 4; ++n) {
                float re = acc_re[m][n][reg], im = acc_im[m][n][reg];
                rp[n * 16] = sqrtf(fmaf(re, re, im * im));
            }
        }
    }
}

// ---------------------------------------------------------------------------
// row softmax of S/2 -> bf16 weights
__global__ __launch_bounds__(256) void k_softmax(const float* __restrict__ S,
                                                 unsigned short* __restrict__ Wout) {
    __shared__ float red[8];
    const size_t row = blockIdx.x;
    const int tid = threadIdx.x;
    const float4* __restrict__ p4 = (const float4*)(S + row * NN);
    float4 v[4];
    float vmax = -1e30f;
#pragma unroll
    for (int u = 0; u < 4; ++u) {
        v[u] = p4[u * 256 + tid];
        vmax = fmaxf(vmax, fmaxf(fmaxf(v[u].x, v[u].y), fmaxf(v[u].z, v[u].w)));
    }
    for (int off = 32; off > 0; off >>= 1) vmax = fmaxf(vmax, __shfl_down(vmax, off, 64));
    if ((tid & 63) == 0) red[tid >> 6] = vmax;
    __syncthreads();
    const float bmax = fmaxf(fmaxf(red[0], red[1]), fmaxf(red[2], red[3]));
    float s = 0.f;
#pragma unroll
    for (int u = 0; u < 4; ++u) {
        v[u].x = __expf((v[u].x - bmax) * 0.5f);
        v[u].y = __expf((v[u].y - bmax) * 0.5f);
        v[u].z = __expf((v[u].z - bmax) * 0.5f);
        v[u].w = __expf((v[u].w - bmax) * 0.5f);
        s += (v[u].x + v[u].y) + (v[u].z + v[u].w);
    }
    for (int off = 32; off > 0; off >>= 1) s += __shfl_down(s, off, 64);
    if ((tid & 63) == 0) red[4 + (tid >> 6)] = s;
    __syncthreads();
    const float rinv = 1.0f / ((red[4] + red[5]) + (red[6] + red[7]));
    ushort4* __restrict__ o4 = (ushort4*)(Wout + row * NN);
#pragma unroll
    for (int u = 0; u < 4; ++u) {
        ushort4 w;
        w.x = f2bf(v[u].x * rinv);
        w.y = f2bf(v[u].y * rinv);
        w.z = f2bf(v[u].z * rinv);
        w.w = f2bf(v[u].w * rinv);
        o4[u * 256 + tid] = w;
    }
}

// ---------------------------------------------------------------------------
// xbT[b][d][t] = bf16(x[b][t][d])  (64x64 tiles through LDS)
__global__ __launch_bounds__(256) void k_xpose(const float* __restrict__ x,
                                               u16* __restrict__ xbT) {
    __shared__ u16 st[64][72];
    const int b = blockIdx.z;
    const int t0 = blockIdx.x * 64;
    const int d0 = blockIdx.y * 64;
    const int tid = threadIdx.x;
#pragma unroll
    for (int u = 0; u < 4; ++u) {
        int idx = tid + u * 256;               // 0..1023
        int tl = idx >> 4, d4 = (idx & 15) * 4;
        float4 v = *(const float4*)(x + ((size_t)(b * NN) + t0 + tl) * DD + d0 + d4);
        st[tl][d4 + 0] = f2bf(v.x);
        st[tl][d4 + 1] = f2bf(v.y);
        st[tl][d4 + 2] = f2bf(v.z);
        st[tl][d4 + 3] = f2bf(v.w);
    }
    __syncthreads();
#pragma unroll
    for (int u = 0; u < 2; ++u) {
        int e = tid + u * 256;                 // 0..511
        int dl = e >> 3, t8 = (e & 7) * 8;
        union { u16 h[8]; uint4 q; } o;
#pragma unroll
        for (int j = 0; j < 8; ++j) o.h[j] = st[t8 + j][dl];
        *(uint4*)(xbT + ((size_t)(b * DD) + d0 + dl) * NN + t0 + t8) = o.q;
    }
}

// ---------------------------------------------------------------------------
// mixed = Ssoft @ x : bf16 MFMA, A=Ssoft[m][k], Bsrc=xbT[n][k], 128x128 tile
__global__ __launch_bounds__(256) void k_mixed_mfma(const u16* __restrict__ Ws,
                                                    const u16* __restrict__ xbT,
                                                    float* __restrict__ mixed) {
    __shared__ u16 As[128 * 64];
    __shared__ u16 Bs[128 * 64];
    const int b = blockIdx.z;
    const int brow = blockIdx.y * 128;
    const int bcol = blockIdx.x * 128;
    const int tid = threadIdx.x;
    const int lane = tid & 63;
    const int wave = tid >> 6;
    const int wr = (wave >> 1) * 64;
    const int wc = (wave & 1) * 64;
    const int fr = lane & 15;
    const int fk = (lane >> 4) * 8;

    const u16* __restrict__ Arow = Ws + (size_t)(b * NN + brow) * NN;
    const u16* __restrict__ Brow = xbT + ((size_t)(b * DD) + bcol) * NN;

    f32x4 acc[4][4];
#pragma unroll
    for (int m = 0; m < 4; ++m)
#pragma unroll
        for (int n = 0; n < 4; ++n) acc[m][n] = (f32x4)0.f;

    for (int kc = 0; kc < NN / 64; ++kc) {
        const int k0 = kc * 64;
        __syncthreads();
#pragma unroll
        for (int it = 0; it < 4; ++it) {
            int e = tid + it * 256;
            int row = e >> 3, ch = e & 7;
            gl2lds(Arow + (size_t)row * NN + k0 + ch * 8, &As[e * 8]);
            gl2lds(Brow + (size_t)row * NN + k0 + ch * 8, &Bs[e * 8]);
        }
        __syncthreads();
#pragma unroll
        for (int kk = 0; kk < 2; ++kk) {
            bf16x8 av[4], bv[4];
#pragma unroll
            for (int m = 0; m < 4; ++m)
                av[m] = *(const bf16x8*)&As[(wr + m * 16 + fr) * 64 + kk * 32 + fk];
#pragma unroll
            for (int n = 0; n < 4; ++n)
                bv[n] = *(const bf16x8*)&Bs[(wc + n * 16 + fr) * 64 + kk * 32 + fk];
#pragma unroll
            for (int m = 0; m < 4; ++m)
#pragma unroll
                for (int n = 0; n < 4; ++n)
                    acc[m][n] = __builtin_amdgcn_mfma_f32_16x16x32_bf16(av[m], bv[n], acc[m][n], 0, 0, 0);
        }
    }

    float* __restrict__ ob = mixed + (size_t)b * NN * DD;
#pragma unroll
    for (int m = 0; m < 4; ++m) {
#pragma unroll
        for (int reg = 0; reg < 4; ++reg) {
            int r = brow + wr + m * 16 + (lane >> 4) * 4 + reg;
            float* __restrict__ rp = ob + (size_t)r * DD + bcol + wc + fr;
#pragma unroll
            for (int n = 0; n < 4; ++n) rp[n * 16] = acc[m][n][reg];
        }
    }
}

// ---------------------------------------------------------------------------
// h = x + 0.3*(mixed - x); LayerNorm(D) * gamma + beta
__global__ __launch_bounds__(256) void k_ln(const float* __restrict__ x,
                                            const float* __restrict__ mixed,
                                            const float* __restrict__ gamma,
                                            const float* __restrict__ beta,
                                            float* __restrict__ out) {
    __shared__ float red[8];
    const size_t row = blockIdx.x;
    const int tid = threadIdx.x;
    const float* __restrict__ xr = x + row * DD;
    const float* __restrict__ mr = mixed + row * DD;
    float x0 = xr[tid], x1 = xr[tid + 256];
    float h0 = fmaf(0.3f, mr[tid] - x0, x0);
    float h1 = fmaf(0.3f, mr[tid + 256] - x1, x1);
    float s = h0 + h1;
    float sq = fmaf(h0, h0, h1 * h1);
    for (int off = 32; off > 0; off >>= 1) {
        s += __shfl_down(s, off, 64);
        sq += __shfl_down(sq, off, 64);
    }
    if ((tid & 63) == 0) { red[tid >> 6] = s; red[4 + (tid >> 6)] = sq; }
    __syncthreads();
    const float mu = ((red[0] + red[1]) + (red[2] + red[3])) * (1.0f / DD);
    const float var = ((red[4] + red[5]) + (red[6] + red[7])) * (1.0f / DD) - mu * mu;
    const float rstd = rsqrtf(var + 1e-5f);
    out[row * DD + tid] = fmaf((h0 - mu) * rstd, gamma[tid], beta[tid]);
    out[row * DD + tid + 256] = fmaf((h1 - mu) * rstd, gamma[tid + 256], beta[tid + 256]);
}

// ---------------------------------------------------------------------------
extern "C" void kernel_launch(void* const* d_in, const int* in_sizes, int n_in,
                              void* d_out, int out_size, void* d_ws, size_t ws_size,
                              hipStream_t stream) {
    const float* x     = (const float*)d_in[0];
    const float* Wspec = (const float*)d_in[1];
    const float* gamma = (const float*)d_in[2];
    const float* beta  = (const float*)d_in[3];
    float* out  = (float*)d_out;                       // [B][N][D]
    float* Sout = out + (size_t)BB * NN * DD;          // [B][N][N]

    char* ws = (char*)d_ws;
    float* M     = (float*)(ws + M_OFF);
    u32*   XfW   = (u32*)(ws + XF_OFF);
    u16*   Xf    = (u16*)(ws + XF_OFF);
    u16*   Ssoft = (u16*)(ws + SS_OFF);
    u16*   xbT   = (u16*)(ws + XT_OFF);
    float* mixed = (float*)(ws + MX_OFF);

    hipLaunchKernelGGL(k_build_M, dim3(512), dim3(320), 0, stream, Wspec, M);
    hipLaunchKernelGGL(k_proj_norm, dim3(NN / 16, BB), dim3(320), 0, stream, x, M, XfW);
    hipLaunchKernelGGL(k_gram_mfma, dim3(NN / 128, NN / 128, BB), dim3(256), 0, stream, Xf, Sout);
    hipLaunchKernelGGL(k_softmax, dim3(BB * NN), dim3(256), 0, stream, Sout, Ssoft);
    hipLaunchKernelGGL(k_xpose, dim3(NN / 64, DD / 64, BB), dim3(256), 0, stream, x, xbT);
    hipLaunchKernelGGL(k_mixed_mfma, dim3(DD / 128, NN / 128, BB), dim3(256), 0, stream, Ssoft, xbT, mixed);
    hipLaunchKernelGGL(k_ln, dim3(BB * NN), dim3(256), 0, stream, x, mixed, gamma, beta, out);
}

// Round 5
// 498.327 us; speedup vs baseline: 3.3663x; 1.0618x over previous
//
#include <hip/hip_runtime.h>
#include <hip/hip_bf16.h>
#include <math.h>

#define BB 2
#define NN 4096
#define DD 512
#define FF 257
#define FP 288            // padded complex freq bins
#define KK2 (2*FP)        // 576 bf16 along K for gram
#define PI_F 3.14159265358979323846f

typedef __attribute__((ext_vector_type(4))) float f32x4;
typedef __attribute__((ext_vector_type(8))) short bf16x8;
typedef unsigned int u32;
typedef unsigned short u16;

// ---- workspace layout (bytes) ----
#define M_OFF   0u          // float2 M[512][257]           = 1,052,672
#define XF_OFF  1052672u    // bf16 Xf[2][4096][576]        = 9,437,184
#define SS_OFF  10489856u   // bf16 Ssoft[2][4096][4096]    = 67,108,864
#define XT_OFF  77598720u   // bf16 xbT[2][512][4096]       = 8,388,608
#define MX_OFF  85987328u   // f32 mixed[2][4096][512]      = 16,777,216  (end 102,764,544)

#define AS1 __attribute__((address_space(1)))
#define AS3 __attribute__((address_space(3)))

static __device__ __forceinline__ void gl2lds(const u16* g, u16* l) {
    __builtin_amdgcn_global_load_lds((const AS1 u32*)(unsigned long long)g,
                                     (AS3 u32*)(unsigned)(unsigned long long)l,
                                     16, 0, 0);
}

static __device__ __forceinline__ unsigned short f2bf(float f) {
    unsigned int u = __float_as_uint(f);
    unsigned int r = (u + 0x7fffu + ((u >> 16) & 1u)) >> 16;   // RNE
    return (unsigned short)r;
}
static __device__ __forceinline__ float bf2f(unsigned short s) {
    return __uint_as_float(((unsigned int)s) << 16);
}

// (re,im) bf16 pair per dword -> (im, -re)
static __device__ __forceinline__ bf16x8 conj_swap(bf16x8 a) {
    union { bf16x8 v; u32 u[4]; } s, d;
    s.v = a;
#pragma unroll
    for (int i = 0; i < 4; ++i) {
        u32 w = s.u[i];
        d.u[i] = ((w >> 16) | (w << 16)) ^ 0x80000000u;
    }
    return d.v;
}

// ---------------------------------------------------------------------------
// M[d][g] = sum_f W[g,f] * exp(-2*pi*i*f*d/512)   (float2, [512][257])
__global__ __launch_bounds__(320) void k_build_M(const float* __restrict__ W,
                                                 float* __restrict__ M) {
    __shared__ float twr[512], twi[512];
    const int d = blockIdx.x;
    const int tid = threadIdx.x;
    for (int k = tid; k < 512; k += 320) {
        float ang = -(2.0f * PI_F / 512.0f) * (float)k;
        float s, c;
        sincosf(ang, &s, &c);
        twr[k] = c; twi[k] = s;
    }
    __syncthreads();
    const int g = tid;
    if (g < FF) {
        float re = 0.f, im = 0.f;
        const float* __restrict__ wrow = W + g * FF;
        for (int f = 0; f < FF; ++f) {
            float w = wrow[f];
            int k = (f * d) & 511;
            re = fmaf(w, twr[k], re);
            im = fmaf(w, twi[k], im);
        }
        ((float2*)M)[d * FF + g] = make_float2(re, im);
    }
}

// ---------------------------------------------------------------------------
// Per token: x_hat[g] = sum_d x[t,d]*M[d][g]; normalize; write bf16 interleaved
// Xf[b][t][2g]=re, [2g+1]=im, zero pad g in [257,288).
__global__ __launch_bounds__(320) void k_proj_norm(const float* __restrict__ x,
                                                   const float* __restrict__ M,
                                                   u32* __restrict__ Xf) {
    __shared__ float xs[16][512];
    __shared__ float ssq[16];
    const int b = blockIdx.y;
    const int t0 = blockIdx.x * 16;
    const int tid = threadIdx.x;
    const float* __restrict__ xp = x + ((size_t)(b * NN + t0)) * DD;
    for (int i4 = tid; i4 < 16 * 512 / 4; i4 += 320) {
        float4 v = ((const float4*)xp)[i4];
        *(float4*)&xs[0][i4 * 4] = v;
    }
    if (tid < 16) ssq[tid] = 0.f;
    __syncthreads();

    const int g = tid;
    float accr[16], acci[16];
#pragma unroll
    for (int t = 0; t < 16; ++t) { accr[t] = 0.f; acci[t] = 0.f; }

    if (g < FF) {
        const float2* __restrict__ M2 = (const float2*)M;
        for (int d = 0; d < DD; d += 4) {
            float2 m0 = M2[(d + 0) * FF + g];
            float2 m1 = M2[(d + 1) * FF + g];
            float2 m2 = M2[(d + 2) * FF + g];
            float2 m3 = M2[(d + 3) * FF + g];
#pragma unroll
            for (int t = 0; t < 16; ++t) {
                float4 xv = *(const float4*)&xs[t][d];
                float r = accr[t], i = acci[t];
                r = fmaf(xv.x, m0.x, r); i = fmaf(xv.x, m0.y, i);
                r = fmaf(xv.y, m1.x, r); i = fmaf(xv.y, m1.y, i);
                r = fmaf(xv.z, m2.x, r); i = fmaf(xv.z, m2.y, i);
                r = fmaf(xv.w, m3.x, r); i = fmaf(xv.w, m3.y, i);
                accr[t] = r; acci[t] = i;
            }
        }
    }
#pragma unroll
    for (int t = 0; t < 16; ++t) {
        float v = (g < FF) ? fmaf(accr[t], accr[t], acci[t] * acci[t]) : 0.f;
        for (int off = 32; off > 0; off >>= 1) v += __shfl_down(v, off, 64);
        if ((tid & 63) == 0) atomicAdd(&ssq[t], v);
    }
    __syncthreads();
    if (g < FP) {
#pragma unroll
        for (int t = 0; t < 16; ++t) {
            u32 w = 0u;
            if (g < FF) {
                float rn = rsqrtf(ssq[t] + 1e-8f);
                w = (u32)f2bf(accr[t] * rn) | ((u32)f2bf(acci[t] * rn) << 16);
            }
            Xf[((size_t)(b * NN + t0 + t)) * FP + g] = w;
        }
    }
}

// ---------------------------------------------------------------------------
// S = |Xn Xn^H| via bf16 MFMA. 128x128 tile, BK=64, 4 waves, dual accumulators.
// Bank-conflict fix: swizzled global source + linear LDS + swizzled ds_read.
__global__ __launch_bounds__(256) void k_gram_mfma(const u16* __restrict__ Xf,
                                                   float* __restrict__ Sout) {
    __shared__ u16 Af[128 * 64];
    __shared__ u16 Bf[128 * 64];
    const int b = blockIdx.z;
    const int brow = blockIdx.y * 128;
    const int bcol = blockIdx.x * 128;
    const int tid = threadIdx.x;
    const int lane = tid & 63;
    const int wave = tid >> 6;
    const int wr = (wave >> 1) * 64;
    const int wc = (wave & 1) * 64;
    const int fr = lane & 15;
    const int q  = lane >> 4;
    const int sw = lane & 7;

    const u16* __restrict__ Arow = Xf + (size_t)(b * NN + brow) * KK2;
    const u16* __restrict__ Brow = Xf + (size_t)(b * NN + bcol) * KK2;

    int srow[4], soff[4];
#pragma unroll
    for (int it = 0; it < 4; ++it) {
        int e = tid + it * 256;
        int row = e >> 3, ch = e & 7;
        srow[it] = row;
        soff[it] = (ch ^ (row & 7)) * 8;
    }
    const int cs0 = (q ^ sw) * 8;
    const int cs1 = ((4 + q) ^ sw) * 8;

    f32x4 acc_re[4][4], acc_im[4][4];
#pragma unroll
    for (int m = 0; m < 4; ++m)
#pragma unroll
        for (int n = 0; n < 4; ++n) {
            acc_re[m][n] = (f32x4)0.f;
            acc_im[m][n] = (f32x4)0.f;
        }

    int rA[4], rB[4];
#pragma unroll
    for (int m = 0; m < 4; ++m) rA[m] = (wr + m * 16 + fr) * 64;
#pragma unroll
    for (int n = 0; n < 4; ++n) rB[n] = (wc + n * 16 + fr) * 64;

    for (int kc = 0; kc < KK2 / 64; ++kc) {
        const int k0 = kc * 64;
        __syncthreads();
#pragma unroll
        for (int it = 0; it < 4; ++it) {
            int e = tid + it * 256;
            gl2lds(Arow + (size_t)srow[it] * KK2 + k0 + soff[it], &Af[e * 8]);
            gl2lds(Brow + (size_t)srow[it] * KK2 + k0 + soff[it], &Bf[e * 8]);
        }
        __syncthreads();
#pragma unroll
        for (int kk = 0; kk < 2; ++kk) {
            const int cs = kk ? cs1 : cs0;
            bf16x8 av[4], bv[4], gv[4];
#pragma unroll
            for (int m = 0; m < 4; ++m)
                av[m] = *(const bf16x8*)&Af[rA[m] + cs];
#pragma unroll
            for (int n = 0; n < 4; ++n)
                bv[n] = *(const bf16x8*)&Bf[rB[n] + cs];
#pragma unroll
            for (int m = 0; m < 4; ++m) gv[m] = conj_swap(av[m]);
#pragma unroll
            for (int m = 0; m < 4; ++m)
#pragma unroll
                for (int n = 0; n < 4; ++n) {
                    acc_re[m][n] = __builtin_amdgcn_mfma_f32_16x16x32_bf16(av[m], bv[n], acc_re[m][n], 0, 0, 0);
                    acc_im[m][n] = __builtin_amdgcn_mfma_f32_16x16x32_bf16(gv[m], bv[n], acc_im[m][n], 0, 0, 0);
                }
        }
    }

    float* __restrict__ Sb = Sout + (size_t)b * NN * NN;
#pragma unroll
    for (int m = 0; m < 4; ++m) {
#pragma unroll
        for (int reg = 0; reg < 4; ++reg) {
            int r = brow + wr + m * 16 + q * 4 + reg;
            float* __restrict__ rp = Sb + (size_t)r * NN + bcol + wc + fr;
#pragma unroll
            for (int n = 0; n < 4; ++n) {
                float re = acc_re[m][n][reg], im = acc_im[m][n][reg];
                rp[n * 16] = sqrtf(fmaf(re, re, im * im));
            }
        }
    }
}

// ---------------------------------------------------------------------------
// row softmax of S/2 -> bf16 weights
__global__ __launch_bounds__(256) void k_softmax(const float* __restrict__ S,
                                                 unsigned short* __restrict__ Wout) {
    __shared__ float red[8];
    const size_t row = blockIdx.x;
    const int tid = threadIdx.x;
    const float4* __restrict__ p4 = (const float4*)(S + row * NN);
    float4 v[4];
    float vmax = -1e30f;
#pragma unroll
    for (int u = 0; u < 4; ++u) {
        v[u] = p4[u * 256 + tid];
        vmax = fmaxf(vmax, fmaxf(fmaxf(v[u].x, v[u].y), fmaxf(v[u].z, v[u].w)));
    }
    for (int off = 32; off > 0; off >>= 1) vmax = fmaxf(vmax, __shfl_down(vmax, off, 64));
    if ((tid & 63) == 0) red[tid >> 6] = vmax;
    __syncthreads();
    const float bmax = fmaxf(fmaxf(red[0], red[1]), fmaxf(red[2], red[3]));
    float s = 0.f;
#pragma unroll
    for (int u = 0; u < 4; ++u) {
        v[u].x = __expf((v[u].x - bmax) * 0.5f);
        v[u].y = __expf((v[u].y - bmax) * 0.5f);
        v[u].z = __expf((v[u].z - bmax) * 0.5f);
        v[u].w = __expf((v[u].w - bmax) * 0.5f);
        s += (v[u].x + v[u].y) + (v[u].z + v[u].w);
    }
    for (int off = 32; off > 0; off >>= 1) s += __shfl_down(s, off, 64);
    if ((tid & 63) == 0) red[4 + (tid >> 6)] = s;
    __syncthreads();
    const float rinv = 1.0f / ((red[4] + red[5]) + (red[6] + red[7]));
    ushort4* __restrict__ o4 = (ushort4*)(Wout + row * NN);
#pragma unroll
    for (int u = 0; u < 4; ++u) {
        ushort4 w;
        w.x = f2bf(v[u].x * rinv);
        w.y = f2bf(v[u].y * rinv);
        w.z = f2bf(v[u].z * rinv);
        w.w = f2bf(v[u].w * rinv);
        o4[u * 256 + tid] = w;
    }
}

// ---------------------------------------------------------------------------
// xbT[b][d][t] = bf16(x[b][t][d])  (64x64 tiles through LDS)
__global__ __launch_bounds__(256) void k_xpose(const float* __restrict__ x,
                                               u16* __restrict__ xbT) {
    __shared__ u16 st[64][72];
    const int b = blockIdx.z;
    const int t0 = blockIdx.x * 64;
    const int d0 = blockIdx.y * 64;
    const int tid = threadIdx.x;
#pragma unroll
    for (int u = 0; u < 4; ++u) {
        int idx = tid + u * 256;               // 0..1023
        int tl = idx >> 4, d4 = (idx & 15) * 4;
        float4 v = *(const float4*)(x + ((size_t)(b * NN) + t0 + tl) * DD + d0 + d4);
        st[tl][d4 + 0] = f2bf(v.x);
        st[tl][d4 + 1] = f2bf(v.y);
        st[tl][d4 + 2] = f2bf(v.z);
        st[tl][d4 + 3] = f2bf(v.w);
    }
    __syncthreads();
#pragma unroll
    for (int u = 0; u < 2; ++u) {
        int e = tid + u * 256;                 // 0..511
        int dl = e >> 3, t8 = (e & 7) * 8;
        union { u16 h[8]; uint4 q; } o;
#pragma unroll
        for (int j = 0; j < 8; ++j) o.h[j] = st[t8 + j][dl];
        *(uint4*)(xbT + ((size_t)(b * DD) + d0 + dl) * NN + t0 + t8) = o.q;
    }
}

// ---------------------------------------------------------------------------
// mixed = Ssoft @ x : bf16 MFMA. BM=64 x BN=128 (512 blocks), swizzled staging.
__global__ __launch_bounds__(256) void k_mixed_mfma(const u16* __restrict__ Ws,
                                                    const u16* __restrict__ xbT,
                                                    float* __restrict__ mixed) {
    __shared__ u16 As[64 * 64];
    __shared__ u16 Bs[128 * 64];
    const int b = blockIdx.z;
    const int brow = blockIdx.y * 64;
    const int bcol = blockIdx.x * 128;
    const int tid = threadIdx.x;
    const int lane = tid & 63;
    const int wave = tid >> 6;
    const int wr = (wave >> 1) * 32;
    const int wc = (wave & 1) * 64;
    const int fr = lane & 15;
    const int q  = lane >> 4;
    const int sw = lane & 7;

    const u16* __restrict__ Arow = Ws + (size_t)(b * NN + brow) * NN;
    const u16* __restrict__ Brow = xbT + ((size_t)(b * DD) + bcol) * NN;

    const int cs0 = (q ^ sw) * 8;
    const int cs1 = ((4 + q) ^ sw) * 8;

    f32x4 acc[2][4];
#pragma unroll
    for (int m = 0; m < 2; ++m)
#pragma unroll
        for (int n = 0; n < 4; ++n) acc[m][n] = (f32x4)0.f;

    int rA[2], rB[4];
#pragma unroll
    for (int m = 0; m < 2; ++m) rA[m] = (wr + m * 16 + fr) * 64;
#pragma unroll
    for (int n = 0; n < 4; ++n) rB[n] = (wc + n * 16 + fr) * 64;

    for (int kc = 0; kc < NN / 64; ++kc) {
        const int k0 = kc * 64;
        __syncthreads();
#pragma unroll
        for (int it = 0; it < 2; ++it) {        // A: 64 rows x 8 chunks
            int e = tid + it * 256;
            int row = e >> 3, ch = e & 7;
            gl2lds(Arow + (size_t)row * NN + k0 + (ch ^ (row & 7)) * 8, &As[e * 8]);
        }
#pragma unroll
        for (int it = 0; it < 4; ++it) {        // B: 128 rows x 8 chunks
            int e = tid + it * 256;
            int row = e >> 3, ch = e & 7;
            gl2lds(Brow + (size_t)row * NN + k0 + (ch ^ (row & 7)) * 8, &Bs[e * 8]);
        }
        __syncthreads();
#pragma unroll
        for (int kk = 0; kk < 2; ++kk) {
            const int cs = kk ? cs1 : cs0;
            bf16x8 av[2], bv[4];
#pragma unroll
            for (int m = 0; m < 2; ++m)
                av[m] = *(const bf16x8*)&As[rA[m] + cs];
#pragma unroll
            for (int n = 0; n < 4; ++n)
                bv[n] = *(const bf16x8*)&Bs[rB[n] + cs];
#pragma unroll
            for (int m = 0; m < 2; ++m)
#pragma unroll
                for (int n = 0; n < 4; ++n)
                    acc[m][n] = __builtin_amdgcn_mfma_f32_16x16x32_bf16(av[m], bv[n], acc[m][n], 0, 0, 0);
        }
    }

    float* __restrict__ ob = mixed + (size_t)b * NN * DD;
#pragma unroll
    for (int m = 0; m < 2; ++m) {
#pragma unroll
        for (int reg = 0; reg < 4; ++reg) {
            int r = brow + wr + m * 16 + q * 4 + reg;
            float* __restrict__ rp = ob + (size_t)r * DD + bcol + wc + fr;
#pragma unroll
            for (int n = 0; n < 4; ++n) rp[n * 16] = acc[m][n][reg];
        }
    }
}

// ---------------------------------------------------------------------------
// h = x + 0.3*(mixed - x); LayerNorm(D) * gamma + beta
__global__ __launch_bounds__(256) void k_ln(const float* __restrict__ x,
                                            const float* __restrict__ mixed,
                                            const float* __restrict__ gamma,
                                            const float* __restrict__ beta,
                                            float* __restrict__ out) {
    __shared__ float red[8];
    const size_t row = blockIdx.x;
    const int tid = threadIdx.x;
    const float* __restrict__ xr = x + row * DD;
    const float* __restrict__ mr = mixed + row * DD;
    float x0 = xr[tid], x1 = xr[tid + 256];
    float h0 = fmaf(0.3f, mr[tid] - x0, x0);
    float h1 = fmaf(0.3f, mr[tid + 256] - x1, x1);
    float s = h0 + h1;
    float sq = fmaf(h0, h0, h1 * h1);
    for (int off = 32; off > 0; off >>= 1) {
        s += __shfl_down(s, off, 64);
        sq += __shfl_down(sq, off, 64);
    }
    if ((tid & 63) == 0) { red[tid >> 6] = s; red[4 + (tid >> 6)] = sq; }
    __syncthreads();
    const float mu = ((red[0] + red[1]) + (red[2] + red[3])) * (1.0f / DD);
    const float var = ((red[4] + red[5]) + (red[6] + red[7])) * (1.0f / DD) - mu * mu;
    const float rstd = rsqrtf(var + 1e-5f);
    out[row * DD + tid] = fmaf((h0 - mu) * rstd, gamma[tid], beta[tid]);
    out[row * DD + tid + 256] = fmaf((h1 - mu) * rstd, gamma[tid + 256], beta[tid + 256]);
}

// ---------------------------------------------------------------------------
extern "C" void kernel_launch(void* const* d_in, const int* in_sizes, int n_in,
                              void* d_out, int out_size, void* d_ws, size_t ws_size,
                              hipStream_t stream) {
    const float* x     = (const float*)d_in[0];
    const float* Wspec = (const float*)d_in[1];
    const float* gamma = (const float*)d_in[2];
    const float* beta  = (const float*)d_in[3];
    float* out  = (float*)d_out;                       // [B][N][D]
    float* Sout = out + (size_t)BB * NN * DD;          // [B][N][N]

    char* ws = (char*)d_ws;
    float* M     = (float*)(ws + M_OFF);
    u32*   XfW   = (u32*)(ws + XF_OFF);
    u16*   Xf    = (u16*)(ws + XF_OFF);
    u16*   Ssoft = (u16*)(ws + SS_OFF);
    u16*   xbT   = (u16*)(ws + XT_OFF);
    float* mixed = (float*)(ws + MX_OFF);

    hipLaunchKernelGGL(k_build_M, dim3(512), dim3(320), 0, stream, Wspec, M);
    hipLaunchKernelGGL(k_proj_norm, dim3(NN / 16, BB), dim3(320), 0, stream, x, M, XfW);
    hipLaunchKernelGGL(k_gram_mfma, dim3(NN / 128, NN / 128, BB), dim3(256), 0, stream, Xf, Sout);
    hipLaunchKernelGGL(k_softmax, dim3(BB * NN), dim3(256), 0, stream, Sout, Ssoft);
    hipLaunchKernelGGL(k_xpose, dim3(NN / 64, DD / 64, BB), dim3(256), 0, stream, x, xbT);
    hipLaunchKernelGGL(k_mixed_mfma, dim3(DD / 128, NN / 64, BB), dim3(256), 0, stream, Ssoft, xbT, mixed);
    hipLaunchKernelGGL(k_ln, dim3(BB * NN), dim3(256), 0, stream, x, mixed, gamma, beta, out);
}

// Round 7
// 386.503 us; speedup vs baseline: 4.3403x; 1.2893x over previous
//
#include <hip/hip_runtime.h>
#include <hip/hip_bf16.h>
#include <math.h>

#define BB 2
#define NN 4096
#define DD 512
#define FF 257
#define FP 288            // padded complex freq bins
#define KK2 (2*FP)        // 576 bf16 along K for gram
#define NT 528            // 32*33/2 upper-tri 128x128 tiles per batch
#define PI_F 3.14159265358979323846f

typedef __attribute__((ext_vector_type(4))) float f32x4;
typedef __attribute__((ext_vector_type(8))) short bf16x8;
typedef unsigned int u32;
typedef unsigned short u16;

// ---- workspace layout (bytes) ----
#define MT_OFF  0u          // bf16 Mt[576][512]            = 589,824 (pad to 1,052,672)
#define XF_OFF  1052672u    // bf16 xhat/Xf[8192][576]      = 9,437,184
#define SS_OFF  10489856u   // bf16 Ssoft[2][4096][4096]    = 67,108,864
                            //   (pre-softmax: aliased as xb bf16[8192][512]=8,388,608
                            //    + norms f32[8192]=32,768)
#define NR_OFF  (SS_OFF + 8388608u)
#define XT_OFF  77598720u   // bf16 xbT[2][512][4096]       = 8,388,608
#define MX_OFF  85987328u   // f32 mixed[2][4096][512]      = 16,777,216  (end 102,764,544)

#define AS1 __attribute__((address_space(1)))
#define AS3 __attribute__((address_space(3)))

static __device__ __forceinline__ void gl2lds(const u16* g, u16* l) {
    __builtin_amdgcn_global_load_lds((const AS1 u32*)(unsigned long long)g,
                                     (AS3 u32*)(unsigned)(unsigned long long)l,
                                     16, 0, 0);
}

static __device__ __forceinline__ unsigned short f2bf(float f) {
    unsigned int u = __float_as_uint(f);
    unsigned int r = (u + 0x7fffu + ((u >> 16) & 1u)) >> 16;   // RNE
    return (unsigned short)r;
}
static __device__ __forceinline__ float bf2f(unsigned short s) {
    return __uint_as_float(((unsigned int)s) << 16);
}

// (re,im) bf16 pair per dword -> (im, -re)
static __device__ __forceinline__ bf16x8 conj_swap(bf16x8 a) {
    union { bf16x8 v; u32 u[4]; } s, d;
    s.v = a;
#pragma unroll
    for (int i = 0; i < 4; ++i) {
        u32 w = s.u[i];
        d.u[i] = ((w >> 16) | (w << 16)) ^ 0x80000000u;
    }
    return d.v;
}

// ---------------------------------------------------------------------------
// zero Mt pad rows [514,576) and norms[8192]
__global__ __launch_bounds__(256) void k_zero(float* __restrict__ norms,
                                              u16* __restrict__ Mt) {
    int i = blockIdx.x * 256 + threadIdx.x;        // grid 124*256 = 31744
    if (i < 8192) norms[i] = 0.f;
    Mt[514 * 512 + i] = 0;                         // 62 rows * 512 = 31744
}

// ---------------------------------------------------------------------------
// Mt[2g][d] = Re sum_f W[g,f] e^{-2pi i f d/512}; Mt[2g+1][d] = Im ...  (bf16)
__global__ __launch_bounds__(512) void k_build_Mt(const float* __restrict__ W,
                                                  u16* __restrict__ Mt) {
    __shared__ float twr[512], twi[512], wrow[FF];
    const int g = blockIdx.x;          // 0..256
    const int d = threadIdx.x;         // 0..511
    {
        float s, c;
        sincosf(-(2.0f * PI_F / 512.0f) * (float)d, &s, &c);
        twr[d] = c; twi[d] = s;
    }
    for (int f = d; f < FF; f += 512) wrow[f] = W[g * FF + f];
    __syncthreads();
    float re = 0.f, im = 0.f;
    for (int f = 0; f < FF; ++f) {
        float w = wrow[f];
        int k = (f * d) & 511;
        re = fmaf(w, twr[k], re);
        im = fmaf(w, twi[k], im);
    }
    Mt[(size_t)(2 * g) * 512 + d]     = f2bf(re);
    Mt[(size_t)(2 * g + 1) * 512 + d] = f2bf(im);
}

// ---------------------------------------------------------------------------
// xb = bf16(x), flat [8192*512]
__global__ __launch_bounds__(256) void k_xcast(const float* __restrict__ x,
                                               u16* __restrict__ xb) {
    const size_t i = ((size_t)blockIdx.x * 256 + threadIdx.x) * 8;
    float4 a = *(const float4*)(x + i);
    float4 b = *(const float4*)(x + i + 4);
    union { u16 h[8]; uint4 q; } o;
    o.h[0] = f2bf(a.x); o.h[1] = f2bf(a.y); o.h[2] = f2bf(a.z); o.h[3] = f2bf(a.w);
    o.h[4] = f2bf(b.x); o.h[5] = f2bf(b.y); o.h[6] = f2bf(b.z); o.h[7] = f2bf(b.w);
    *(uint4*)(xb + i) = o.q;
}

// ---------------------------------------------------------------------------
// xhat[r][g2] = sum_d xb[r][d]*Mt[g2][d], bf16 out; norms[r] += row sumsq.
// BM=128, BN=64, BK=64, 4 waves (wr = wave*32).
__global__ __launch_bounds__(256) void k_proj_mfma(const u16* __restrict__ xb,
                                                   const u16* __restrict__ Mt,
                                                   u16* __restrict__ xhat,
                                                   float* __restrict__ norms) {
    __shared__ u16 As[128 * 64];
    __shared__ u16 Bs[64 * 64];
    const int prow = blockIdx.y * 128;
    const int gcol = blockIdx.x * 64;
    const int tid = threadIdx.x;
    const int lane = tid & 63;
    const int wave = tid >> 6;
    const int wr = wave * 32;
    const int fr = lane & 15;
    const int q  = lane >> 4;
    const int sw = lane & 7;

    const u16* __restrict__ Arow = xb + (size_t)prow * DD;
    const u16* __restrict__ Brow = Mt + (size_t)gcol * DD;

    const int cs0 = (q ^ sw) * 8;
    const int cs1 = ((4 + q) ^ sw) * 8;

    f32x4 acc[2][4];
#pragma unroll
    for (int m = 0; m < 2; ++m)
#pragma unroll
        for (int n = 0; n < 4; ++n) acc[m][n] = (f32x4)0.f;

    int rA[2], rB[4];
#pragma unroll
    for (int m = 0; m < 2; ++m) rA[m] = (wr + m * 16 + fr) * 64;
#pragma unroll
    for (int n = 0; n < 4; ++n) rB[n] = (n * 16 + fr) * 64;

    for (int kc = 0; kc < DD / 64; ++kc) {
        const int k0 = kc * 64;
        __syncthreads();
#pragma unroll
        for (int it = 0; it < 4; ++it) {          // A: 128 rows x 8 chunks
            int e = tid + it * 256;
            int row = e >> 3, ch = e & 7;
            gl2lds(Arow + (size_t)row * DD + k0 + (ch ^ (row & 7)) * 8, &As[e * 8]);
        }
#pragma unroll
        for (int it = 0; it < 2; ++it) {          // B: 64 rows x 8 chunks
            int e = tid + it * 256;
            int row = e >> 3, ch = e & 7;
            gl2lds(Brow + (size_t)row * DD + k0 + (ch ^ (row & 7)) * 8, &Bs[e * 8]);
        }
        __syncthreads();
#pragma unroll
        for (int kk = 0; kk < 2; ++kk) {
            const int cs = kk ? cs1 : cs0;
            bf16x8 av[2], bv[4];
#pragma unroll
            for (int m = 0; m < 2; ++m) av[m] = *(const bf16x8*)&As[rA[m] + cs];
#pragma unroll
            for (int n = 0; n < 4; ++n) bv[n] = *(const bf16x8*)&Bs[rB[n] + cs];
#pragma unroll
            for (int m = 0; m < 2; ++m)
#pragma unroll
                for (int n = 0; n < 4; ++n)
                    acc[m][n] = __builtin_amdgcn_mfma_f32_16x16x32_bf16(av[m], bv[n], acc[m][n], 0, 0, 0);
        }
    }

#pragma unroll
    for (int m = 0; m < 2; ++m) {
#pragma unroll
        for (int reg = 0; reg < 4; ++reg) {
            const int r = prow + wr + m * 16 + q * 4 + reg;
            u16* __restrict__ rp = xhat + (size_t)r * KK2 + gcol + fr;
            float sq = 0.f;
#pragma unroll
            for (int n = 0; n < 4; ++n) {
                float v = acc[m][n][reg];
                rp[n * 16] = f2bf(v);
                sq = fmaf(v, v, sq);
            }
            sq += __shfl_xor(sq, 1);
            sq += __shfl_xor(sq, 2);
            sq += __shfl_xor(sq, 4);
            sq += __shfl_xor(sq, 8);
            if (fr == 0) atomicAdd(&norms[r], sq);
        }
    }
}

// ---------------------------------------------------------------------------
// Xf[row][*] *= rsqrt(norms[row] + eps)   (in place, u32 = 2 bf16)
__global__ __launch_bounds__(256) void k_normalize(u32* __restrict__ Xf,
                                                   const float* __restrict__ norms) {
    const int row = blockIdx.x * 8 + (threadIdx.x >> 5);
    const int l = threadIdx.x & 31;
    const float rn = rsqrtf(norms[row] + 1e-8f);
    u32* __restrict__ p = Xf + (size_t)row * FP;
#pragma unroll
    for (int u = 0; u < 9; ++u) {
        u32 w = p[u * 32 + l];
        float lo = bf2f((u16)(w & 0xffffu)) * rn;
        float hi = bf2f((u16)(w >> 16)) * rn;
        p[u * 32 + l] = (u32)f2bf(lo) | ((u32)f2bf(hi) << 16);
    }
}

// ---------------------------------------------------------------------------
// S = |Xn Xn^H|, symmetric: only upper-tri+diag 128x128 tiles computed;
// off-diag tiles also write the mirror via LDS transpose.
__global__ __launch_bounds__(256) void k_gram_mfma(const u16* __restrict__ Xf,
                                                   float* __restrict__ Sout) {
    __shared__ u16 Af[128 * 64];
    __shared__ u16 Bf[128 * 64];
    __shared__ float trs[32][129];
    // triangular decode
    int i = (int)blockIdx.x;
    int b = 0;
    if (i >= NT) { b = 1; i -= NT; }
    int a = 0;
    while (i >= 32 - a) { i -= 32 - a; ++a; }
    const int brow = a * 128;
    const int bcol = (a + i) * 128;

    const int tid = threadIdx.x;
    const int lane = tid & 63;
    const int wave = tid >> 6;
    const int wr = (wave >> 1) * 64;
    const int wc = (wave & 1) * 64;
    const int fr = lane & 15;
    const int q  = lane >> 4;
    const int sw = lane & 7;

    const u16* __restrict__ Arow = Xf + (size_t)(b * NN + brow) * KK2;
    const u16* __restrict__ Brow = Xf + (size_t)(b * NN + bcol) * KK2;

    int srow[4], soff[4];
#pragma unroll
    for (int it = 0; it < 4; ++it) {
        int e = tid + it * 256;
        int row = e >> 3, ch = e & 7;
        srow[it] = row;
        soff[it] = (ch ^ (row & 7)) * 8;
    }
    const int cs0 = (q ^ sw) * 8;
    const int cs1 = ((4 + q) ^ sw) * 8;

    f32x4 acc_re[4][4], acc_im[4][4];
#pragma unroll
    for (int m = 0; m < 4; ++m)
#pragma unroll
        for (int n = 0; n < 4; ++n) {
            acc_re[m][n] = (f32x4)0.f;
            acc_im[m][n] = (f32x4)0.f;
        }

    int rA[4], rB[4];
#pragma unroll
    for (int m = 0; m < 4; ++m) rA[m] = (wr + m * 16 + fr) * 64;
#pragma unroll
    for (int n = 0; n < 4; ++n) rB[n] = (wc + n * 16 + fr) * 64;

    for (int kc = 0; kc < KK2 / 64; ++kc) {
        const int k0 = kc * 64;
        __syncthreads();
#pragma unroll
        for (int it = 0; it < 4; ++it) {
            int e = tid + it * 256;
            gl2lds(Arow + (size_t)srow[it] * KK2 + k0 + soff[it], &Af[e * 8]);
            gl2lds(Brow + (size_t)srow[it] * KK2 + k0 + soff[it], &Bf[e * 8]);
        }
        __syncthreads();
#pragma unroll
        for (int kk = 0; kk < 2; ++kk) {
            const int cs = kk ? cs1 : cs0;
            bf16x8 av[4], bv[4], gv[4];
#pragma unroll
            for (int m = 0; m < 4; ++m) av[m] = *(const bf16x8*)&Af[rA[m] + cs];
#pragma unroll
            for (int n = 0; n < 4; ++n) bv[n] = *(const bf16x8*)&Bf[rB[n] + cs];
#pragma unroll
            for (int m = 0; m < 4; ++m) gv[m] = conj_swap(av[m]);
#pragma unroll
            for (int m = 0; m < 4; ++m)
#pragma unroll
                for (int n = 0; n < 4; ++n) {
                    acc_re[m][n] = __builtin_amdgcn_mfma_f32_16x16x32_bf16(av[m], bv[n], acc_re[m][n], 0, 0, 0);
                    acc_im[m][n] = __builtin_amdgcn_mfma_f32_16x16x32_bf16(gv[m], bv[n], acc_im[m][n], 0, 0, 0);
                }
        }
    }

    float* __restrict__ Sb = Sout + (size_t)b * NN * NN;
    // direct store of the (brow, bcol) tile
#pragma unroll
    for (int m = 0; m < 4; ++m) {
#pragma unroll
        for (int reg = 0; reg < 4; ++reg) {
            int r = brow + wr + m * 16 + q * 4 + reg;
            float* __restrict__ rp = Sb + (size_t)r * NN + bcol + wc + fr;
#pragma unroll
            for (int n = 0; n < 4; ++n) {
                float re = acc_re[m][n][reg], im = acc_im[m][n][reg];
                rp[n * 16] = sqrtf(fmaf(re, re, im * im));
            }
        }
    }
    if (brow == bcol) return;

    // mirror store of the (bcol, brow) tile via 4-phase LDS transpose
#pragma unroll
    for (int p = 0; p < 4; ++p) {
        __syncthreads();
        if ((wave >> 1) == (p >> 1)) {
            const int mbase = (p & 1) * 2;
#pragma unroll
            for (int mm = 0; mm < 2; ++mm) {
                const int m = mbase + mm;
                const int i0 = mm * 16 + q * 4;     // (m*16+q*4) - (p&1)*32
#pragma unroll
                for (int reg = 0; reg < 4; ++reg) {
#pragma unroll
                    for (int n = 0; n < 4; ++n) {
                        float re = acc_re[m][n][reg], im = acc_im[m][n][reg];
                        trs[i0 + reg][wc + n * 16 + fr] = sqrtf(fmaf(re, re, im * im));
                    }
                }
            }
        }
        __syncthreads();
        const int j0 = (tid & 7) * 4;
#pragma unroll
        for (int u = 0; u < 4; ++u) {
            const int mr = u * 32 + (tid >> 3);
            float4 v;
            v.x = trs[j0 + 0][mr];
            v.y = trs[j0 + 1][mr];
            v.z = trs[j0 + 2][mr];
            v.w = trs[j0 + 3][mr];
            *(float4*)(Sb + (size_t)(bcol + mr) * NN + brow + p * 32 + j0) = v;
        }
    }
}

// ---------------------------------------------------------------------------
// row softmax of S/2 -> bf16 weights
__global__ __launch_bounds__(256) void k_softmax(const float* __restrict__ S,
                                                 unsigned short* __restrict__ Wout) {
    __shared__ float red[8];
    const size_t row = blockIdx.x;
    const int tid = threadIdx.x;
    const float4* __restrict__ p4 = (const float4*)(S + row * NN);
    float4 v[4];
    float vmax = -1e30f;
#pragma unroll
    for (int u = 0; u < 4; ++u) {
        v[u] = p4[u * 256 + tid];
        vmax = fmaxf(vmax, fmaxf(fmaxf(v[u].x, v[u].y), fmaxf(v[u].z, v[u].w)));
    }
    for (int off = 32; off > 0; off >>= 1) vmax = fmaxf(vmax, __shfl_down(vmax, off, 64));
    if ((tid & 63) == 0) red[tid >> 6] = vmax;
    __syncthreads();
    const float bmax = fmaxf(fmaxf(red[0], red[1]), fmaxf(red[2], red[3]));
    float s = 0.f;
#pragma unroll
    for (int u = 0; u < 4; ++u) {
        v[u].x = __expf((v[u].x - bmax) * 0.5f);
        v[u].y = __expf((v[u].y - bmax) * 0.5f);
        v[u].z = __expf((v[u].z - bmax) * 0.5f);
        v[u].w = __expf((v[u].w - bmax) * 0.5f);
        s += (v[u].x + v[u].y) + (v[u].z + v[u].w);
    }
    for (int off = 32; off > 0; off >>= 1) s += __shfl_down(s, off, 64);
    if ((tid & 63) == 0) red[4 + (tid >> 6)] = s;
    __syncthreads();
    const float rinv = 1.0f / ((red[4] + red[5]) + (red[6] + red[7]));
    ushort4* __restrict__ o4 = (ushort4*)(Wout + row * NN);
#pragma unroll
    for (int u = 0; u < 4; ++u) {
        ushort4 w;
        w.x = f2bf(v[u].x * rinv);
        w.y = f2bf(v[u].y * rinv);
        w.z = f2bf(v[u].z * rinv);
        w.w = f2bf(v[u].w * rinv);
        o4[u * 256 + tid] = w;
    }
}

// ---------------------------------------------------------------------------
// xbT[b][d][t] = bf16(x[b][t][d])  (64x64 tiles through LDS)
__global__ __launch_bounds__(256) void k_xpose(const float* __restrict__ x,
                                               u16* __restrict__ xbT) {
    __shared__ u16 st[64][72];
    const int b = blockIdx.z;
    const int t0 = blockIdx.x * 64;
    const int d0 = blockIdx.y * 64;
    const int tid = threadIdx.x;
#pragma unroll
    for (int u = 0; u < 4; ++u) {
        int idx = tid + u * 256;               // 0..1023
        int tl = idx >> 4, d4 = (idx & 15) * 4;
        float4 v = *(const float4*)(x + ((size_t)(b * NN) + t0 + tl) * DD + d0 + d4);
        st[tl][d4 + 0] = f2bf(v.x);
        st[tl][d4 + 1] = f2bf(v.y);
        st[tl][d4 + 2] = f2bf(v.z);
        st[tl][d4 + 3] = f2bf(v.w);
    }
    __syncthreads();
#pragma unroll
    for (int u = 0; u < 2; ++u) {
        int e = tid + u * 256;                 // 0..511
        int dl = e >> 3, t8 = (e & 7) * 8;
        union { u16 h[8]; uint4 q; } o;
#pragma unroll
        for (int j = 0; j < 8; ++j) o.h[j] = st[t8 + j][dl];
        *(uint4*)(xbT + ((size_t)(b * DD) + d0 + dl) * NN + t0 + t8) = o.q;
    }
}

// ---------------------------------------------------------------------------
// mixed = Ssoft @ x : bf16 MFMA. BM=64 x BN=128 (512 blocks), swizzled staging.
__global__ __launch_bounds__(256) void k_mixed_mfma(const u16* __restrict__ Ws,
                                                    const u16* __restrict__ xbT,
                                                    float* __restrict__ mixed) {
    __shared__ u16 As[64 * 64];
    __shared__ u16 Bs[128 * 64];
    const int b = blockIdx.z;
    const int brow = blockIdx.y * 64;
    const int bcol = blockIdx.x * 128;
    const int tid = threadIdx.x;
    const int lane = tid & 63;
    const int wave = tid >> 6;
    const int wr = (wave >> 1) * 32;
    const int wc = (wave & 1) * 64;
    const int fr = lane & 15;
    const int q  = lane >> 4;
    const int sw = lane & 7;

    const u16* __restrict__ Arow = Ws + (size_t)(b * NN + brow) * NN;
    const u16* __restrict__ Brow = xbT + ((size_t)(b * DD) + bcol) * NN;

    const int cs0 = (q ^ sw) * 8;
    const int cs1 = ((4 + q) ^ sw) * 8;

    f32x4 acc[2][4];
#pragma unroll
    for (int m = 0; m < 2; ++m)
#pragma unroll
        for (int n = 0; n < 4; ++n) acc[m][n] = (f32x4)0.f;

    int rA[2], rB[4];
#pragma unroll
    for (int m = 0; m < 2; ++m) rA[m] = (wr + m * 16 + fr) * 64;
#pragma unroll
    for (int n = 0; n < 4; ++n) rB[n] = (wc + n * 16 + fr) * 64;

    for (int kc = 0; kc < NN / 64; ++kc) {
        const int k0 = kc * 64;
        __syncthreads();
#pragma unroll
        for (int it = 0; it < 2; ++it) {        // A: 64 rows x 8 chunks
            int e = tid + it * 256;
            int row = e >> 3, ch = e & 7;
            gl2lds(Arow + (size_t)row * NN + k0 + (ch ^ (row & 7)) * 8, &As[e * 8]);
        }
#pragma unroll
        for (int it = 0; it < 4; ++it) {        // B: 128 rows x 8 chunks
            int e = tid + it * 256;
            int row = e >> 3, ch = e & 7;
            gl2lds(Brow + (size_t)row * NN + k0 + (ch ^ (row & 7)) * 8, &Bs[e * 8]);
        }
        __syncthreads();
#pragma unroll
        for (int kk = 0; kk < 2; ++kk) {
            const int cs = kk ? cs1 : cs0;
            bf16x8 av[2], bv[4];
#pragma unroll
            for (int m = 0; m < 2; ++m) av[m] = *(const bf16x8*)&As[rA[m] + cs];
#pragma unroll
            for (int n = 0; n < 4; ++n) bv[n] = *(const bf16x8*)&Bs[rB[n] + cs];
#pragma unroll
            for (int m = 0; m < 2; ++m)
#pragma unroll
                for (int n = 0; n < 4; ++n)
                    acc[m][n] = __builtin_amdgcn_mfma_f32_16x16x32_bf16(av[m], bv[n], acc[m][n], 0, 0, 0);
        }
    }

    float* __restrict__ ob = mixed + (size_t)b * NN * DD;
#pragma unroll
    for (int m = 0; m < 2; ++m) {
#pragma unroll
        for (int reg = 0; reg < 4; ++reg) {
            int r = brow + wr + m * 16 + q * 4 + reg;
            float* __restrict__ rp = ob + (size_t)r * DD + bcol + wc + fr;
#pragma unroll
            for (int n = 0; n < 4; ++n) rp[n * 16] = acc[m][n][reg];
        }
    }
}

// ---------------------------------------------------------------------------
// h = x + 0.3*(mixed - x); LayerNorm(D) * gamma + beta
__global__ __launch_bounds__(256) void k_ln(const float* __restrict__ x,
                                            const float* __restrict__ mixed,
                                            const float* __restrict__ gamma,
                                            const float* __restrict__ beta,
                                            float* __restrict__ out) {
    __shared__ float red[8];
    const size_t row = blockIdx.x;
    const int tid = threadIdx.x;
    const float* __restrict__ xr = x + row * DD;
    const float* __restrict__ mr = mixed + row * DD;
    float x0 = xr[tid], x1 = xr[tid + 256];
    float h0 = fmaf(0.3f, mr[tid] - x0, x0);
    float h1 = fmaf(0.3f, mr[tid + 256] - x1, x1);
    float s = h0 + h1;
    float sq = fmaf(h0, h0, h1 * h1);
    for (int off = 32; off > 0; off >>= 1) {
        s += __shfl_down(s, off, 64);
        sq += __shfl_down(sq, off, 64);
    }
    if ((tid & 63) == 0) { red[tid >> 6] = s; red[4 + (tid >> 6)] = sq; }
    __syncthreads();
    const float mu = ((red[0] + red[1]) + (red[2] + red[3])) * (1.0f / DD);
    const float var = ((red[4] + red[5]) + (red[6] + red[7])) * (1.0f / DD) - mu * mu;
    const float rstd = rsqrtf(var + 1e-5f);
    out[row * DD + tid] = fmaf((h0 - mu) * rstd, gamma[tid], beta[tid]);
    out[row * DD + tid + 256] = fmaf((h1 - mu) * rstd, gamma[tid + 256], beta[tid + 256]);
}

// ---------------------------------------------------------------------------
extern "C" void kernel_launch(void* const* d_in, const int* in_sizes, int n_in,
                              void* d_out, int out_size, void* d_ws, size_t ws_size,
                              hipStream_t stream) {
    const float* x     = (const float*)d_in[0];
    const float* Wspec = (const float*)d_in[1];
    const float* gamma = (const float*)d_in[2];
    const float* beta  = (const float*)d_in[3];
    float* out  = (float*)d_out;                       // [B][N][D]
    float* Sout = out + (size_t)BB * NN * DD;          // [B][N][N]

    char* ws = (char*)d_ws;
    u16*   Mt    = (u16*)(ws + MT_OFF);
    u16*   Xf    = (u16*)(ws + XF_OFF);       // xhat, then normalized Xf
    u32*   XfW   = (u32*)(ws + XF_OFF);
    u16*   xb    = (u16*)(ws + SS_OFF);       // aliased: pre-softmax scratch
    float* norms = (float*)(ws + NR_OFF);     // aliased: pre-softmax scratch
    u16*   Ssoft = (u16*)(ws + SS_OFF);
    u16*   xbT   = (u16*)(ws + XT_OFF);
    float* mixed = (float*)(ws + MX_OFF);

    hipLaunchKernelGGL(k_zero, dim3(124), dim3(256), 0, stream, norms, Mt);
    hipLaunchKernelGGL(k_build_Mt, dim3(257), dim3(512), 0, stream, Wspec, Mt);
    hipLaunchKernelGGL(k_xcast, dim3(2048), dim3(256), 0, stream, x, xb);
    hipLaunchKernelGGL(k_proj_mfma, dim3(KK2 / 64, (BB * NN) / 128), dim3(256), 0, stream,
                       xb, Mt, Xf, norms);
    hipLaunchKernelGGL(k_normalize, dim3(BB * NN / 8), dim3(256), 0, stream, XfW, norms);
    hipLaunchKernelGGL(k_gram_mfma, dim3(BB * NT), dim3(256), 0, stream, Xf, Sout);
    hipLaunchKernelGGL(k_softmax, dim3(BB * NN), dim3(256), 0, stream, Sout, Ssoft);
    hipLaunchKernelGGL(k_xpose, dim3(NN / 64, DD / 64, BB), dim3(256), 0, stream, x, xbT);
    hipLaunchKernelGGL(k_mixed_mfma, dim3(DD / 128, NN / 64, BB), dim3(256), 0, stream, Ssoft, xbT, mixed);
    hipLaunchKernelGGL(k_ln, dim3(BB * NN), dim3(256), 0, stream, x, mixed, gamma, beta, out);
}